// Round 9
// baseline (822.535 us; speedup 1.0000x reference)
//
#include <hip/hip_runtime.h>
#include <hip/hip_bf16.h>
#include <math.h>

#define S_LEN 2048
#define HID   2048
#define NH    32
#define NKV   8
#define HD    64
#define KVW   (NKV * HD)   // 512

typedef __attribute__((ext_vector_type(8))) short bf16x8;
typedef __attribute__((ext_vector_type(4))) float f32x4;
typedef unsigned short u16;

__device__ __forceinline__ u16 f2bf(float f) {
    return (u16)((__builtin_bit_cast(unsigned, f) + 0x8000u) >> 16);
}
__device__ __forceinline__ float bf2f(u16 v) {
    unsigned u = ((unsigned)v) << 16;
    return __builtin_bit_cast(float, u);
}
__device__ __forceinline__ unsigned pack2bf(float a, float b) {
    unsigned ua = __builtin_bit_cast(unsigned, a) + 0x8000u;
    unsigned ub = __builtin_bit_cast(unsigned, b) + 0x8000u;
    return (ua >> 16) | (ub & 0xFFFF0000u);
}
// async global->LDS, 16B/lane; LDS dest = wave-uniform base + lane*16
__device__ __forceinline__ void stage16(const u16* g, u16* lds_base) {
    __builtin_amdgcn_global_load_lds((const __attribute__((address_space(1))) void*)g,
                                     (__attribute__((address_space(3))) void*)lds_base, 16, 0, 0);
}

// ---------------------------------------------------------------------------
// Elementwise f32 -> bf16 (8 elems/thread).
// ---------------------------------------------------------------------------
__global__ __launch_bounds__(256) void cvt_bf16x8_kernel(const float* __restrict__ X,
                                                         u16* __restrict__ Y, int n8) {
    int i = blockIdx.x * 256 + threadIdx.x;
    if (i >= n8) return;
    const float4* p = (const float4*)(X + (size_t)i * 8);
    float4 a = p[0], b = p[1];
    uint4 o;
    o.x = pack2bf(a.x, a.y);
    o.y = pack2bf(a.z, a.w);
    o.z = pack2bf(b.x, b.y);
    o.w = pack2bf(b.z, b.w);
    *(uint4*)(Y + (size_t)i * 8) = o;
}

// ---------------------------------------------------------------------------
// Transpose+cvt all four weights in one launch. All sources have R=2048 rows.
// ---------------------------------------------------------------------------
__global__ __launch_bounds__(256) void transpose_cvt4(const float* __restrict__ Wq,
                                                      const float* __restrict__ Wk,
                                                      const float* __restrict__ Wv,
                                                      const float* __restrict__ Wo,
                                                      u16* __restrict__ WqkvT,
                                                      u16* __restrict__ WoT) {
    const float* X; u16* Y; int C;
    const int z = blockIdx.z;
    if (z == 0)      { X = Wq; Y = WqkvT;                        C = HID; }
    else if (z == 1) { X = Wo; Y = WoT;                          C = HID; }
    else if (z == 2) { X = Wk; Y = WqkvT + (size_t)2048 * HID;   C = KVW; }
    else             { X = Wv; Y = WqkvT + (size_t)2560 * HID;   C = KVW; }
    const int c0 = blockIdx.x * 32, r0 = blockIdx.y * 32;
    if (c0 >= C) return;
    __shared__ float T[32][33];
    const int tx = threadIdx.x & 31, ty = threadIdx.x >> 5;
#pragma unroll
    for (int i = 0; i < 4; i++)
        T[ty + 8 * i][tx] = X[(size_t)(r0 + ty + 8 * i) * C + c0 + tx];
    __syncthreads();
#pragma unroll
    for (int i = 0; i < 4; i++)
        Y[(size_t)(c0 + ty + 8 * i) * HID + r0 + tx] = f2bf(T[tx][ty + 8 * i]);
}

// ---------------------------------------------------------------------------
// bf16 MFMA GEMM, BM=BN=256, BK=64, 512 threads = 8 waves (2M x 4N), per-wave
// output 128x64 (8x4 fragments of 16x16). LDS 128 KB: TWO K-tile slots
// (A 32KB + B 32KB each), STATICALLY indexed.
// __launch_bounds__(512, 1): the spill-fit across rounds 2-8 shows hipcc's
// 2nd arg acts like CUDA min-blocks/CU with a ~128-VGPR default budget;
// (512,1) -> 1 block/CU -> 2 waves/EU -> 256-VGPR cap (>= the ~210 this
// kernel needs; acc alone is 128). LDS already pins 1 block/CU, so no
// occupancy is lost. Rounds 3/7/8 (caps <=128) spilled acc to scratch:
// VGPR 88 + WRITE_SIZE 131/815 MB.
// Fragment-order chunks (64 lanes x 16B) -> conflict-free ds_read_b128.
// Two-tile schedule per iteration:
//   issue tile t+1 stages (8 gload_lds/thread) -> compute tile t as 4
//   quadrants (12 ds_read + 16 MFMA each, setprio-wrapped) -> vmcnt(0) +
//   s_barrier (drains loads issued a full 4-quadrant block ago) -> repeat
//   with slots swapped.
// EPI=0: fp32 row-major C. EPI=1: fused QKV epilogue (Q / K+RoPE / V^T);
// per-wave 64 cols are head-aligned -> RoPE pair (c,c+32) = frags n, n+2.
// ---------------------------------------------------------------------------
template <int EPI>
__global__ __launch_bounds__(512, 1) void gemm_bf16(const u16* __restrict__ A,
                                                    const u16* __restrict__ Bt,
                                                    float* __restrict__ C,
                                                    u16* __restrict__ Qh,
                                                    u16* __restrict__ Kh,
                                                    u16* __restrict__ Vt,
                                                    int K) {
    __shared__ u16 As[2][16384];   // 32 chunks x 512 u16 per slot (32 KB)
    __shared__ u16 Bs[2][16384];   // 32 chunks x 512 u16 per slot (32 KB)

    // XCD-chunked bijective swizzle (grid 96 / 64 blocks, both % 8 == 0):
    const int tiles = gridDim.x * gridDim.y;
    const int flat = blockIdx.y * gridDim.x + blockIdx.x;
    const int per = tiles >> 3;
    const int swz = (flat & 7) * per + (flat >> 3);
    const int bxx = swz % gridDim.x, byy = swz / gridDim.x;
    const int bm = byy * 256, bn = bxx * 256;

    const int t = threadIdx.x;
    const int w = t >> 6, lane = t & 63;
    const int qd = lane >> 4, r = lane & 15;
    const int wm = w >> 2, wn = w & 3;      // 2M x 4N wave grid
    const bool kblk = (EPI == 1) && (bn >= 2048) && (bn < 2560);
    const int NT = K >> 6;                  // 32 K-tiles

    f32x4 acc[8][4];
#pragma unroll
    for (int m = 0; m < 8; m++)
#pragma unroll
        for (int n = 0; n < 4; n++) {
            acc[m][n][0] = 0.f; acc[m][n][1] = 0.f;
            acc[m][n][2] = 0.f; acc[m][n][3] = 0.f;
        }

// stage tile kt_ into slot s_ (LITERAL 0/1): wave w owns A chunks w*4..w*4+3
// and B chunks w*4..w*4+3; chunk c: rows base+ (c>>1)*16 + r, k = k0+(c&1)*32+qd*8
#define STAGE_TILE(kt_, s_)                                                       \
    {                                                                             \
        const int k0_ = (kt_) * 64;                                               \
        _Pragma("unroll")                                                         \
        for (int l = 0; l < 4; l++) {                                             \
            const int chunk = w * 4 + l;                                          \
            const int tt = chunk >> 1, ss = chunk & 1;                            \
            const u16* ga = A + (size_t)(bm + tt * 16 + r) * K + k0_ + ss * 32 + qd * 8; \
            stage16(ga, &As[s_][chunk * 512]);                                    \
            const u16* gb = Bt + (size_t)(bn + tt * 16 + r) * K + k0_ + ss * 32 + qd * 8; \
            stage16(gb, &Bs[s_][chunk * 512]);                                    \
        }                                                                         \
    }

// compute one quadrant (qm_, qn_ LITERAL 0/1) of slot s_ (LITERAL 0/1):
// A-frags m = qm_*4+i (i<4), kk<2; B-frags n = qn_*2+j (j<2), kk<2; 16 MFMA
#define QUAD(s_, qm_, qn_)                                                        \
    {                                                                             \
        bf16x8 af[4][2], bfv[2][2];                                               \
        _Pragma("unroll")                                                         \
        for (int i = 0; i < 4; i++)                                               \
            _Pragma("unroll")                                                     \
            for (int kk = 0; kk < 2; kk++)                                        \
                af[i][kk] = *(const bf16x8*)&As[s_][((wm * 8 + (qm_) * 4 + i) * 2 + kk) * 512 + lane * 8]; \
        _Pragma("unroll")                                                         \
        for (int j = 0; j < 2; j++)                                               \
            _Pragma("unroll")                                                     \
            for (int kk = 0; kk < 2; kk++)                                        \
                bfv[j][kk] = *(const bf16x8*)&Bs[s_][((wn * 4 + (qn_) * 2 + j) * 2 + kk) * 512 + lane * 8]; \
        __builtin_amdgcn_s_setprio(1);                                            \
        _Pragma("unroll")                                                         \
        for (int i = 0; i < 4; i++)                                               \
            _Pragma("unroll")                                                     \
            for (int j = 0; j < 2; j++)                                           \
                _Pragma("unroll")                                                 \
                for (int kk = 0; kk < 2; kk++)                                    \
                    acc[(qm_) * 4 + i][(qn_) * 2 + j] =                           \
                        __builtin_amdgcn_mfma_f32_16x16x32_bf16(af[i][kk], bfv[j][kk], \
                            acc[(qm_) * 4 + i][(qn_) * 2 + j], 0, 0, 0);          \
        __builtin_amdgcn_s_setprio(0);                                            \
    }

#define WAITBAR                                                                   \
    asm volatile("s_waitcnt vmcnt(0)" ::: "memory");                              \
    __builtin_amdgcn_s_barrier();

    // prologue: tile 0 -> slot 0
    STAGE_TILE(0, 0);
    WAITBAR;

    for (int i2 = 0; i2 < NT / 2; ++i2) {
        const int te = 2 * i2;
        // issue odd tile's loads, then compute even tile (slot 0)
        STAGE_TILE(te + 1, 1);
        QUAD(0, 0, 0) QUAD(0, 0, 1) QUAD(0, 1, 0) QUAD(0, 1, 1)
        WAITBAR;                      // odd tile landed; slot0 reads done
        // issue next even tile's loads (overwrite slot 0), compute odd (slot 1)
        if (te + 2 < NT) STAGE_TILE(te + 2, 0);
        QUAD(1, 0, 0) QUAD(1, 0, 1) QUAD(1, 1, 0) QUAD(1, 1, 1)
        WAITBAR;                      // next even landed; slot1 reads done
    }
#undef STAGE_TILE
#undef QUAD
#undef WAITBAR

    // ---- epilogue ----
    const int row0 = bm + wm * 128;
    const int col0 = bn + wn * 64;
    if (EPI == 0) {
#pragma unroll
        for (int m = 0; m < 8; m++)
#pragma unroll
            for (int n = 0; n < 4; n++)
#pragma unroll
                for (int reg = 0; reg < 4; reg++)
                    C[(size_t)(row0 + m * 16 + qd * 4 + reg) * HID + col0 + n * 16 + r] =
                        acc[m][n][reg];
    } else if (bn < 2048) {
        // Q: bf16 row-major [2048][2048]
#pragma unroll
        for (int m = 0; m < 8; m++)
#pragma unroll
            for (int n = 0; n < 4; n++)
#pragma unroll
                for (int reg = 0; reg < 4; reg++)
                    Qh[(size_t)(row0 + m * 16 + qd * 4 + reg) * HID + col0 + n * 16 + r] =
                        f2bf(acc[m][n][reg]);
    } else if (kblk) {
        // K: fused RoPE. Wave covers one full head (64 cols, head-aligned).
        // Pair (c, c+32): frag n (n=0,1) holds c = n*16+r, frag n+2 holds c+32.
        const int hb = (bn - 2048) + wn * 64;             // head base in Kh row
#pragma unroll
        for (int n = 0; n < 2; n++) {
            const int c0 = n * 16 + r;                    // within-head col 0..31
            const float inv = __expf(-(float)c0 * 0.2878231366242596f);  // 10000^(-c0/32)
#pragma unroll
            for (int m = 0; m < 8; m++)
#pragma unroll
                for (int reg = 0; reg < 4; reg++) {
                    int srow = row0 + m * 16 + qd * 4 + reg;
                    float ang = (float)srow * inv;
                    float cs = cosf(ang), sn = sinf(ang);
                    float k1 = acc[m][n][reg], k2 = acc[m][n + 2][reg];
                    size_t o = (size_t)srow * KVW + hb + c0;
                    Kh[o]      = f2bf(k1 * cs - k2 * sn);
                    Kh[o + 32] = f2bf(k2 * cs + k1 * sn);
                }
        }
    } else {
        // V: bf16 transposed Vt[512][2048]; 4 regs = 4 consecutive m -> 8B store
#pragma unroll
        for (int m = 0; m < 8; m++)
#pragma unroll
            for (int n = 0; n < 4; n++) {
                int nrel = (bn - 2560) + wn * 64 + n * 16 + r;
                int m0 = row0 + m * 16 + qd * 4;
                ushort4 v;
                v.x = f2bf(acc[m][n][0]); v.y = f2bf(acc[m][n][1]);
                v.z = f2bf(acc[m][n][2]); v.w = f2bf(acc[m][n][3]);
                *(ushort4*)(Vt + (size_t)nrel * S_LEN + m0) = v;
            }
    }
}

// ---------------------------------------------------------------------------
// Flash attention, 512 threads (8 waves), 128 q-rows/block, 64-key tiles.
// (unchanged: K double-buffered, V staged same-tile, two barriers per tile.)
// LDS 42 KB -> 3 blocks/CU.
// ---------------------------------------------------------------------------
__global__ __launch_bounds__(512, 6) void attn_mfma(const u16* __restrict__ Qh,
                                                    const u16* __restrict__ K,
                                                    const u16* __restrict__ Vt,
                                                    u16* __restrict__ O) {
    __shared__ u16 Kbuf[2][4096];     // 8 chunks x 512 u16
    __shared__ u16 Vbuf[4096];
    __shared__ u16 P_lds[8][16][72];

    const int w    = threadIdx.x >> 6;            // 0..7
    const int lane = threadIdx.x & 63;
    const int qd   = lane >> 4;
    const int r    = lane & 15;
    const int qb   = 15 - (int)blockIdx.x;        // heavy blocks first
    const int h    = blockIdx.y;
    const int kvh  = h >> 2;
    const int q0w  = qb * 128 + w * 16;           // wave's first q row

    // ---- Q: bf16 load, fp32 RoPE, scale, repack to A-frags ----
    const u16* qrow = Qh + (size_t)(q0w + r) * (NH * HD) + h * HD;
    bf16x8 qlo = *(const bf16x8*)(qrow + qd * 8);
    bf16x8 qhi = *(const bf16x8*)(qrow + 32 + qd * 8);
    float y1[8], y2[8];
    const float spos = (float)(q0w + r);
    const float LN1E4_OVER_32 = 0.2878231366242596f;
#pragma unroll
    for (int i = 0; i < 8; i++) {
        int jj = qd * 8 + i;
        float x1 = bf2f((u16)qlo[i]);
        float x2 = bf2f((u16)qhi[i]);
        float inv = __expf(-(float)jj * LN1E4_OVER_32);
        float ang = spos * inv;
        float c = cosf(ang), sn = sinf(ang);
        y1[i] = (x1 * c - x2 * sn) * 0.125f;
        y2[i] = (x2 * c + x1 * sn) * 0.125f;
    }
    bf16x8 qfrag[2];
    {
        union { unsigned u[4]; bf16x8 v; } a, b;
#pragma unroll
        for (int i = 0; i < 4; i++) {
            a.u[i] = pack2bf(y1[2 * i], y1[2 * i + 1]);
            b.u[i] = pack2bf(y2[2 * i], y2[2 * i + 1]);
        }
        qfrag[0] = a.v; qfrag[1] = b.v;
    }

    bf16x8 ones;
    {
        union { u16 s[8]; bf16x8 v; } u;
#pragma unroll
        for (int i = 0; i < 8; i++) u.s[i] = 0x3F80;
        ones = u.v;
    }

    f32x4 oacc[4];
    f32x4 lacc;
#pragma unroll
    for (int i = 0; i < 4; i++) { oacc[i][0]=0.f; oacc[i][1]=0.f; oacc[i][2]=0.f; oacc[i][3]=0.f; }
    lacc[0]=0.f; lacc[1]=0.f; lacc[2]=0.f; lacc[3]=0.f;

    const int ktmax = 2 * qb + 1;

    // one 16B stage per thread: wave w stages chunk w (nt = w>>1, cc = w&1)
#define STAGE_K(kt_, buf_)                                                        \
    {                                                                             \
        const u16* g = K + (size_t)((kt_) * 64 + (w >> 1) * 16 + r) * KVW         \
                         + kvh * HD + (w & 1) * 32 + qd * 8;                      \
        stage16(g, &Kbuf[buf_][w * 512]);                                         \
    }
#define STAGE_V(kt_)                                                              \
    {                                                                             \
        const u16* g = Vt + (size_t)(kvh * HD + (w >> 1) * 16 + r) * S_LEN        \
                          + (kt_) * 64 + (w & 1) * 32 + qd * 8;                   \
        stage16(g, &Vbuf[w * 512]);                                               \
    }

    STAGE_K(0, 0);
    __syncthreads();
    int cur = 0;

    for (int kt = 0; kt <= ktmax; kt++) {
        STAGE_V(kt);
        if (kt < ktmax) STAGE_K(kt + 1, cur ^ 1);

        // ---- S = Q K^T (16 q x 64 keys), conflict-free ds_read_b128 ----
        f32x4 s[4];
#pragma unroll
        for (int nt = 0; nt < 4; nt++) {
            bf16x8 kf0 = *(const bf16x8*)&Kbuf[cur][(nt * 2 + 0) * 512 + lane * 8];
            bf16x8 kf1 = *(const bf16x8*)&Kbuf[cur][(nt * 2 + 1) * 512 + lane * 8];
            f32x4 z; z[0]=0.f; z[1]=0.f; z[2]=0.f; z[3]=0.f;
            z = __builtin_amdgcn_mfma_f32_16x16x32_bf16(qfrag[0], kf0, z, 0, 0, 0);
            s[nt] = __builtin_amdgcn_mfma_f32_16x16x32_bf16(qfrag[1], kf1, z, 0, 0, 0);
        }

        // ---- causal mask ----
        if (kt * 64 + 63 > q0w) {
#pragma unroll
            for (int nt = 0; nt < 4; nt++) {
                int key = kt * 64 + nt * 16 + r;
#pragma unroll
                for (int reg = 0; reg < 4; reg++) {
                    int qg = q0w + qd * 4 + reg;
                    if (key > qg) s[nt][reg] = -1e30f;
                }
            }
        }

        // ---- p = exp(s) -> per-wave LDS (C-layout -> A-layout) ----
#pragma unroll
        for (int nt = 0; nt < 4; nt++)
#pragma unroll
            for (int reg = 0; reg < 4; reg++)
                P_lds[w][qd * 4 + reg][nt * 16 + r] = f2bf(__expf(s[nt][reg]));

        __syncthreads();   // V tile visible (P is per-wave, needs no barrier)

        // ---- O += P V ; l += P * ones ----
#pragma unroll
        for (int c = 0; c < 2; c++) {
            bf16x8 pf = *(const bf16x8*)&P_lds[w][r][c * 32 + qd * 8];
            lacc = __builtin_amdgcn_mfma_f32_16x16x32_bf16(pf, ones, lacc, 0, 0, 0);
#pragma unroll
            for (int ntd = 0; ntd < 4; ntd++) {
                bf16x8 vf = *(const bf16x8*)&Vbuf[(ntd * 2 + c) * 512 + lane * 8];
                oacc[ntd] = __builtin_amdgcn_mfma_f32_16x16x32_bf16(pf, vf, oacc[ntd], 0, 0, 0);
            }
        }

        __syncthreads();   // buf reads done before next iteration's staging
        cur ^= 1;
    }
#undef STAGE_K
#undef STAGE_V

    // ---- epilogue: O / l, store bf16 ----
    float rl[4];
#pragma unroll
    for (int reg = 0; reg < 4; reg++) rl[reg] = 1.f / lacc[reg];
#pragma unroll
    for (int ntd = 0; ntd < 4; ntd++)
#pragma unroll
        for (int reg = 0; reg < 4; reg++)
            O[(size_t)(q0w + qd * 4 + reg) * (NH * HD) + h * HD + ntd * 16 + r] =
                f2bf(oacc[ntd][reg] * rl[reg]);
}

// ---------------------------------------------------------------------------
// Launch: 5 dispatches.
// ---------------------------------------------------------------------------
extern "C" void kernel_launch(void* const* d_in, const int* in_sizes, int n_in,
                              void* d_out, int out_size, void* d_ws, size_t ws_size,
                              hipStream_t stream) {
    const float* hidden = (const float*)d_in[0];
    const float* Wq = (const float*)d_in[1];
    const float* Wk = (const float*)d_in[2];
    const float* Wv = (const float*)d_in[3];
    const float* Wo = (const float*)d_in[4];
    float* out = (float*)d_out;

    char* ws = (char*)d_ws;
    const size_t MB = 1024 * 1024;
    u16* Hh     = (u16*)(ws + 0 * MB);    // bf16 hidden          [2048][2048]   8 MB
    u16* WqkvT  = (u16*)(ws + 8 * MB);    // bf16 [Wq;Wk;Wv]^T    [3072][2048]  12 MB
    u16* WoT    = (u16*)(ws + 20 * MB);   // bf16 Wo^T            [2048][2048]   8 MB
    u16* Qh     = (u16*)(ws + 28 * MB);   // bf16 Q (no RoPE)     [2048][2048]   8 MB
    u16* Kh     = (u16*)(ws + 36 * MB);   // bf16 K (RoPE'd)      [2048][512]    2 MB
    u16* Vt     = (u16*)(ws + 38 * MB);   // bf16 V^T             [512][2048]    2 MB
    u16* Ob     = WqkvT;                  // attn out, reuses WqkvT (dead after QKV GEMM)

    cvt_bf16x8_kernel<<<(S_LEN * HID / 8 + 255) / 256, 256, 0, stream>>>(hidden, Hh, S_LEN * HID / 8);
    transpose_cvt4<<<dim3(HID / 32, HID / 32, 4), 256, 0, stream>>>(Wq, Wk, Wv, Wo, WqkvT, WoT);

    // fused QKV projection: N = 3072 (Q 2048 | K 512 | V 512), K-RoPE in epilogue
    gemm_bf16<1><<<dim3(3072 / 256, S_LEN / 256), 512, 0, stream>>>(Hh, WqkvT, nullptr, Qh, Kh, Vt, HID);

    attn_mfma<<<dim3(S_LEN / 128, NH), 512, 0, stream>>>(Qh, Kh, Vt, Ob);

    // output projection -> fp32 out
    gemm_bf16<0><<<dim3(HID / 256, S_LEN / 256), 512, 0, stream>>>(Ob, WoT, out, nullptr, nullptr, nullptr, HID);
}

// Round 10
// 296.628 us; speedup vs baseline: 2.7730x; 2.7730x over previous
//
#include <hip/hip_runtime.h>
#include <hip/hip_bf16.h>
#include <math.h>

#define S_LEN 2048
#define HID   2048
#define NH    32
#define NKV   8
#define HD    64
#define KVW   (NKV * HD)   // 512

typedef __attribute__((ext_vector_type(8))) short bf16x8;
typedef __attribute__((ext_vector_type(4))) float f32x4;
typedef unsigned short u16;

__device__ __forceinline__ u16 f2bf(float f) {
    return (u16)((__builtin_bit_cast(unsigned, f) + 0x8000u) >> 16);
}
__device__ __forceinline__ float bf2f(u16 v) {
    unsigned u = ((unsigned)v) << 16;
    return __builtin_bit_cast(float, u);
}
__device__ __forceinline__ unsigned pack2bf(float a, float b) {
    unsigned ua = __builtin_bit_cast(unsigned, a) + 0x8000u;
    unsigned ub = __builtin_bit_cast(unsigned, b) + 0x8000u;
    return (ua >> 16) | (ub & 0xFFFF0000u);
}
// async global->LDS, 16B/lane; LDS dest = wave-uniform base + lane*16
__device__ __forceinline__ void stage16(const u16* g, u16* lds_base) {
    __builtin_amdgcn_global_load_lds((const __attribute__((address_space(1))) void*)g,
                                     (__attribute__((address_space(3))) void*)lds_base, 16, 0, 0);
}

// ---------------------------------------------------------------------------
// Elementwise f32 -> bf16 (8 elems/thread).
// ---------------------------------------------------------------------------
__global__ __launch_bounds__(256) void cvt_bf16x8_kernel(const float* __restrict__ X,
                                                         u16* __restrict__ Y, int n8) {
    int i = blockIdx.x * 256 + threadIdx.x;
    if (i >= n8) return;
    const float4* p = (const float4*)(X + (size_t)i * 8);
    float4 a = p[0], b = p[1];
    uint4 o;
    o.x = pack2bf(a.x, a.y);
    o.y = pack2bf(a.z, a.w);
    o.z = pack2bf(b.x, b.y);
    o.w = pack2bf(b.z, b.w);
    *(uint4*)(Y + (size_t)i * 8) = o;
}

// ---------------------------------------------------------------------------
// Transpose+cvt all four weights in one launch. All sources have R=2048 rows.
// ---------------------------------------------------------------------------
__global__ __launch_bounds__(256) void transpose_cvt4(const float* __restrict__ Wq,
                                                      const float* __restrict__ Wk,
                                                      const float* __restrict__ Wv,
                                                      const float* __restrict__ Wo,
                                                      u16* __restrict__ WqkvT,
                                                      u16* __restrict__ WoT) {
    const float* X; u16* Y; int C;
    const int z = blockIdx.z;
    if (z == 0)      { X = Wq; Y = WqkvT;                        C = HID; }
    else if (z == 1) { X = Wo; Y = WoT;                          C = HID; }
    else if (z == 2) { X = Wk; Y = WqkvT + (size_t)2048 * HID;   C = KVW; }
    else             { X = Wv; Y = WqkvT + (size_t)2560 * HID;   C = KVW; }
    const int c0 = blockIdx.x * 32, r0 = blockIdx.y * 32;
    if (c0 >= C) return;
    __shared__ float T[32][33];
    const int tx = threadIdx.x & 31, ty = threadIdx.x >> 5;
#pragma unroll
    for (int i = 0; i < 4; i++)
        T[ty + 8 * i][tx] = X[(size_t)(r0 + ty + 8 * i) * C + c0 + tx];
    __syncthreads();
#pragma unroll
    for (int i = 0; i < 4; i++)
        Y[(size_t)(c0 + ty + 8 * i) * HID + r0 + tx] = f2bf(T[tx][ty + 8 * i]);
}

// ---------------------------------------------------------------------------
// bf16 MFMA GEMM, BM=BN=128, BK=32, 256 threads = 4 waves (2M x 2N), wave
// tile 64x64. Accumulator: 16 NAMED f32x4 (a00..a33) -- no array, so no
// aggregate-promotion failure (rule: runtime/aggregate acc -> scratch was
// the round-3/7/8/9 spill: VGPR 88 + WRITE_SIZE 131..815 MB).
// LDS: round-6's verified fragment-order layout (A 8 chunks + B 8 chunks of
// 64 lanes x 16B per 32-k slab; chunk c = rows base+c*16+r, k = k0+qd*8),
// double-buffered (32 KB), round-4's verified schedule: stage next slab,
// compute current, ONE __syncthreads per K-step. No setprio, no swizzle,
// no inline asm (all removed to de-confound the spill experiment).
// reads/MFMA = 8 ds_read_b128 : 16 MFMA = 0.5 (vs 0.75 in round 4).
// EPI=0: fp32 row-major C. EPI=1: fused QKV epilogue; per-wave 64 cols are
// head-aligned (HD=64) -> K-RoPE pair (c,c+32) = frags n and n+2, in-lane.
// ---------------------------------------------------------------------------
template <int EPI>
__global__ __launch_bounds__(256, 4) void gemm_bf16(const u16* __restrict__ A,
                                                    const u16* __restrict__ Bt,
                                                    float* __restrict__ C,
                                                    u16* __restrict__ Qh,
                                                    u16* __restrict__ Kh,
                                                    u16* __restrict__ Vt,
                                                    int K) {
    __shared__ u16 As[2][4096];   // 8 chunks x 512 u16 = 8 KB per buf
    __shared__ u16 Bs[2][4096];   // 8 chunks x 512 u16 = 8 KB per buf -> 32 KB

    const int t = threadIdx.x;
    const int w = t >> 6, lane = t & 63;
    const int qd = lane >> 4, r = lane & 15;
    const int wm = w >> 1, wn = w & 1;      // 2M x 2N wave grid, wave tile 64x64
    const int bm = blockIdx.y * 128, bn = blockIdx.x * 128;
    const bool kblk = (EPI == 1) && (bn >= 2048) && (bn < 2560);

    f32x4 a00 = {0.f,0.f,0.f,0.f}, a01 = {0.f,0.f,0.f,0.f},
          a02 = {0.f,0.f,0.f,0.f}, a03 = {0.f,0.f,0.f,0.f},
          a10 = {0.f,0.f,0.f,0.f}, a11 = {0.f,0.f,0.f,0.f},
          a12 = {0.f,0.f,0.f,0.f}, a13 = {0.f,0.f,0.f,0.f},
          a20 = {0.f,0.f,0.f,0.f}, a21 = {0.f,0.f,0.f,0.f},
          a22 = {0.f,0.f,0.f,0.f}, a23 = {0.f,0.f,0.f,0.f},
          a30 = {0.f,0.f,0.f,0.f}, a31 = {0.f,0.f,0.f,0.f},
          a32 = {0.f,0.f,0.f,0.f}, a33 = {0.f,0.f,0.f,0.f};

    // stage one 32-k slab into buf b_: wave w stages A chunks {2w,2w+1} and
    // B chunks {2w,2w+1}; 4 stage16 per thread.
#define STAGE(k0_, b_)                                                          \
    {                                                                           \
        _Pragma("unroll")                                                       \
        for (int l = 0; l < 2; l++) {                                           \
            const int c_ = w * 2 + l;                                           \
            const u16* ga = A + (size_t)(bm + c_ * 16 + r) * K + (k0_) + qd * 8; \
            stage16(ga, &As[b_][c_ * 512]);                                     \
            const u16* gb = Bt + (size_t)(bn + c_ * 16 + r) * K + (k0_) + qd * 8; \
            stage16(gb, &Bs[b_][c_ * 512]);                                     \
        }                                                                       \
    }

    STAGE(0, 0);
    __syncthreads();
    int cur = 0;

    for (int k0 = 0; k0 < K; k0 += 32) {
        if (k0 + 32 < K) STAGE(k0 + 32, cur ^ 1);

        // 8 conflict-free ds_read_b128, then 16 MFMA
        bf16x8 af0 = *(const bf16x8*)&As[cur][(wm * 4 + 0) * 512 + lane * 8];
        bf16x8 af1 = *(const bf16x8*)&As[cur][(wm * 4 + 1) * 512 + lane * 8];
        bf16x8 af2 = *(const bf16x8*)&As[cur][(wm * 4 + 2) * 512 + lane * 8];
        bf16x8 af3 = *(const bf16x8*)&As[cur][(wm * 4 + 3) * 512 + lane * 8];
        bf16x8 bv0 = *(const bf16x8*)&Bs[cur][(wn * 4 + 0) * 512 + lane * 8];
        bf16x8 bv1 = *(const bf16x8*)&Bs[cur][(wn * 4 + 1) * 512 + lane * 8];
        bf16x8 bv2 = *(const bf16x8*)&Bs[cur][(wn * 4 + 2) * 512 + lane * 8];
        bf16x8 bv3 = *(const bf16x8*)&Bs[cur][(wn * 4 + 3) * 512 + lane * 8];

        a00 = __builtin_amdgcn_mfma_f32_16x16x32_bf16(af0, bv0, a00, 0, 0, 0);
        a01 = __builtin_amdgcn_mfma_f32_16x16x32_bf16(af0, bv1, a01, 0, 0, 0);
        a02 = __builtin_amdgcn_mfma_f32_16x16x32_bf16(af0, bv2, a02, 0, 0, 0);
        a03 = __builtin_amdgcn_mfma_f32_16x16x32_bf16(af0, bv3, a03, 0, 0, 0);
        a10 = __builtin_amdgcn_mfma_f32_16x16x32_bf16(af1, bv0, a10, 0, 0, 0);
        a11 = __builtin_amdgcn_mfma_f32_16x16x32_bf16(af1, bv1, a11, 0, 0, 0);
        a12 = __builtin_amdgcn_mfma_f32_16x16x32_bf16(af1, bv2, a12, 0, 0, 0);
        a13 = __builtin_amdgcn_mfma_f32_16x16x32_bf16(af1, bv3, a13, 0, 0, 0);
        a20 = __builtin_amdgcn_mfma_f32_16x16x32_bf16(af2, bv0, a20, 0, 0, 0);
        a21 = __builtin_amdgcn_mfma_f32_16x16x32_bf16(af2, bv1, a21, 0, 0, 0);
        a22 = __builtin_amdgcn_mfma_f32_16x16x32_bf16(af2, bv2, a22, 0, 0, 0);
        a23 = __builtin_amdgcn_mfma_f32_16x16x32_bf16(af2, bv3, a23, 0, 0, 0);
        a30 = __builtin_amdgcn_mfma_f32_16x16x32_bf16(af3, bv0, a30, 0, 0, 0);
        a31 = __builtin_amdgcn_mfma_f32_16x16x32_bf16(af3, bv1, a31, 0, 0, 0);
        a32 = __builtin_amdgcn_mfma_f32_16x16x32_bf16(af3, bv2, a32, 0, 0, 0);
        a33 = __builtin_amdgcn_mfma_f32_16x16x32_bf16(af3, bv3, a33, 0, 0, 0);

        __syncthreads();   // reads of cur done + next-slab loads drained
        cur ^= 1;
    }
#undef STAGE

    // ---- epilogue ----
    const int row0 = bm + wm * 64;
    const int col0 = bn + wn * 64;
    if (EPI == 0) {
#define ST_C(m_, n_, av)                                                        \
        _Pragma("unroll")                                                       \
        for (int reg = 0; reg < 4; reg++)                                       \
            C[(size_t)(row0 + m_ * 16 + qd * 4 + reg) * HID + col0 + n_ * 16 + r] = av[reg];
        ST_C(0,0,a00) ST_C(0,1,a01) ST_C(0,2,a02) ST_C(0,3,a03)
        ST_C(1,0,a10) ST_C(1,1,a11) ST_C(1,2,a12) ST_C(1,3,a13)
        ST_C(2,0,a20) ST_C(2,1,a21) ST_C(2,2,a22) ST_C(2,3,a23)
        ST_C(3,0,a30) ST_C(3,1,a31) ST_C(3,2,a32) ST_C(3,3,a33)
#undef ST_C
    } else if (bn < 2048) {
#define ST_Q(m_, n_, av)                                                        \
        _Pragma("unroll")                                                       \
        for (int reg = 0; reg < 4; reg++)                                       \
            Qh[(size_t)(row0 + m_ * 16 + qd * 4 + reg) * HID + col0 + n_ * 16 + r] = f2bf(av[reg]);
        ST_Q(0,0,a00) ST_Q(0,1,a01) ST_Q(0,2,a02) ST_Q(0,3,a03)
        ST_Q(1,0,a10) ST_Q(1,1,a11) ST_Q(1,2,a12) ST_Q(1,3,a13)
        ST_Q(2,0,a20) ST_Q(2,1,a21) ST_Q(2,2,a22) ST_Q(2,3,a23)
        ST_Q(3,0,a30) ST_Q(3,1,a31) ST_Q(3,2,a32) ST_Q(3,3,a33)
#undef ST_Q
    } else if (kblk) {
        // K: fused RoPE. Wave covers one full head (64 head-aligned cols).
        // Pair (c, c+32): frag n (n=0,1) holds c = n*16+r, frag n+2 holds c+32.
        const int hb = (bn - 2048) + wn * 64;             // head base in Kh row
#define ST_K(m_, n_, av, av2)                                                   \
        {                                                                       \
            const int c0 = n_ * 16 + r;                                         \
            const float inv = __expf(-(float)c0 * 0.2878231366242596f);         \
            _Pragma("unroll")                                                   \
            for (int reg = 0; reg < 4; reg++) {                                 \
                int srow = row0 + m_ * 16 + qd * 4 + reg;                       \
                float ang = (float)srow * inv;                                  \
                float cs = cosf(ang), sn = sinf(ang);                           \
                float k1 = av[reg], k2 = av2[reg];                              \
                size_t o = (size_t)srow * KVW + hb + c0;                        \
                Kh[o]      = f2bf(k1 * cs - k2 * sn);                           \
                Kh[o + 32] = f2bf(k2 * cs + k1 * sn);                           \
            }                                                                   \
        }
        ST_K(0,0,a00,a02) ST_K(0,1,a01,a03)
        ST_K(1,0,a10,a12) ST_K(1,1,a11,a13)
        ST_K(2,0,a20,a22) ST_K(2,1,a21,a23)
        ST_K(3,0,a30,a32) ST_K(3,1,a31,a33)
#undef ST_K
    } else {
        // V: bf16 transposed Vt[512][2048]; 4 regs = 4 consecutive m -> 8B store
#define ST_V(m_, n_, av)                                                        \
        {                                                                       \
            int nrel = (bn - 2560) + wn * 64 + n_ * 16 + r;                     \
            int m0 = row0 + m_ * 16 + qd * 4;                                   \
            ushort4 v;                                                          \
            v.x = f2bf(av[0]); v.y = f2bf(av[1]);                               \
            v.z = f2bf(av[2]); v.w = f2bf(av[3]);                               \
            *(ushort4*)(Vt + (size_t)nrel * S_LEN + m0) = v;                    \
        }
        ST_V(0,0,a00) ST_V(0,1,a01) ST_V(0,2,a02) ST_V(0,3,a03)
        ST_V(1,0,a10) ST_V(1,1,a11) ST_V(1,2,a12) ST_V(1,3,a13)
        ST_V(2,0,a20) ST_V(2,1,a21) ST_V(2,2,a22) ST_V(2,3,a23)
        ST_V(3,0,a30) ST_V(3,1,a31) ST_V(3,2,a32) ST_V(3,3,a33)
#undef ST_V
    }
}

// ---------------------------------------------------------------------------
// Flash attention, 512 threads (8 waves), 128 q-rows/block, 64-key tiles.
// (verified round-2 version: K double-buffered, V staged same-tile, two
// barriers per tile.) LDS 42 KB -> 3 blocks/CU.
// ---------------------------------------------------------------------------
__global__ __launch_bounds__(512, 6) void attn_mfma(const u16* __restrict__ Qh,
                                                    const u16* __restrict__ K,
                                                    const u16* __restrict__ Vt,
                                                    u16* __restrict__ O) {
    __shared__ u16 Kbuf[2][4096];     // 8 chunks x 512 u16
    __shared__ u16 Vbuf[4096];
    __shared__ u16 P_lds[8][16][72];

    const int w    = threadIdx.x >> 6;            // 0..7
    const int lane = threadIdx.x & 63;
    const int qd   = lane >> 4;
    const int r    = lane & 15;
    const int qb   = 15 - (int)blockIdx.x;        // heavy blocks first
    const int h    = blockIdx.y;
    const int kvh  = h >> 2;
    const int q0w  = qb * 128 + w * 16;           // wave's first q row

    // ---- Q: bf16 load, fp32 RoPE, scale, repack to A-frags ----
    const u16* qrow = Qh + (size_t)(q0w + r) * (NH * HD) + h * HD;
    bf16x8 qlo = *(const bf16x8*)(qrow + qd * 8);
    bf16x8 qhi = *(const bf16x8*)(qrow + 32 + qd * 8);
    float y1[8], y2[8];
    const float spos = (float)(q0w + r);
    const float LN1E4_OVER_32 = 0.2878231366242596f;
#pragma unroll
    for (int i = 0; i < 8; i++) {
        int jj = qd * 8 + i;
        float x1 = bf2f((u16)qlo[i]);
        float x2 = bf2f((u16)qhi[i]);
        float inv = __expf(-(float)jj * LN1E4_OVER_32);
        float ang = spos * inv;
        float c = cosf(ang), sn = sinf(ang);
        y1[i] = (x1 * c - x2 * sn) * 0.125f;
        y2[i] = (x2 * c + x1 * sn) * 0.125f;
    }
    bf16x8 qfrag[2];
    {
        union { unsigned u[4]; bf16x8 v; } a, b;
#pragma unroll
        for (int i = 0; i < 4; i++) {
            a.u[i] = pack2bf(y1[2 * i], y1[2 * i + 1]);
            b.u[i] = pack2bf(y2[2 * i], y2[2 * i + 1]);
        }
        qfrag[0] = a.v; qfrag[1] = b.v;
    }

    bf16x8 ones;
    {
        union { u16 s[8]; bf16x8 v; } u;
#pragma unroll
        for (int i = 0; i < 8; i++) u.s[i] = 0x3F80;
        ones = u.v;
    }

    f32x4 oacc[4];
    f32x4 lacc;
#pragma unroll
    for (int i = 0; i < 4; i++) { oacc[i][0]=0.f; oacc[i][1]=0.f; oacc[i][2]=0.f; oacc[i][3]=0.f; }
    lacc[0]=0.f; lacc[1]=0.f; lacc[2]=0.f; lacc[3]=0.f;

    const int ktmax = 2 * qb + 1;

    // one 16B stage per thread: wave w stages chunk w (nt = w>>1, cc = w&1)
#define STAGE_K(kt_, buf_)                                                        \
    {                                                                             \
        const u16* g = K + (size_t)((kt_) * 64 + (w >> 1) * 16 + r) * KVW         \
                         + kvh * HD + (w & 1) * 32 + qd * 8;                      \
        stage16(g, &Kbuf[buf_][w * 512]);                                         \
    }
#define STAGE_V(kt_)                                                              \
    {                                                                             \
        const u16* g = Vt + (size_t)(kvh * HD + (w >> 1) * 16 + r) * S_LEN        \
                          + (kt_) * 64 + (w & 1) * 32 + qd * 8;                   \
        stage16(g, &Vbuf[w * 512]);                                               \
    }

    STAGE_K(0, 0);
    __syncthreads();
    int cur = 0;

    for (int kt = 0; kt <= ktmax; kt++) {
        STAGE_V(kt);
        if (kt < ktmax) STAGE_K(kt + 1, cur ^ 1);

        // ---- S = Q K^T (16 q x 64 keys), conflict-free ds_read_b128 ----
        f32x4 s[4];
#pragma unroll
        for (int nt = 0; nt < 4; nt++) {
            bf16x8 kf0 = *(const bf16x8*)&Kbuf[cur][(nt * 2 + 0) * 512 + lane * 8];
            bf16x8 kf1 = *(const bf16x8*)&Kbuf[cur][(nt * 2 + 1) * 512 + lane * 8];
            f32x4 z; z[0]=0.f; z[1]=0.f; z[2]=0.f; z[3]=0.f;
            z = __builtin_amdgcn_mfma_f32_16x16x32_bf16(qfrag[0], kf0, z, 0, 0, 0);
            s[nt] = __builtin_amdgcn_mfma_f32_16x16x32_bf16(qfrag[1], kf1, z, 0, 0, 0);
        }

        // ---- causal mask ----
        if (kt * 64 + 63 > q0w) {
#pragma unroll
            for (int nt = 0; nt < 4; nt++) {
                int key = kt * 64 + nt * 16 + r;
#pragma unroll
                for (int reg = 0; reg < 4; reg++) {
                    int qg = q0w + qd * 4 + reg;
                    if (key > qg) s[nt][reg] = -1e30f;
                }
            }
        }

        // ---- p = exp(s) -> per-wave LDS (C-layout -> A-layout) ----
#pragma unroll
        for (int nt = 0; nt < 4; nt++)
#pragma unroll
            for (int reg = 0; reg < 4; reg++)
                P_lds[w][qd * 4 + reg][nt * 16 + r] = f2bf(__expf(s[nt][reg]));

        __syncthreads();   // V tile visible (P is per-wave, needs no barrier)

        // ---- O += P V ; l += P * ones ----
#pragma unroll
        for (int c = 0; c < 2; c++) {
            bf16x8 pf = *(const bf16x8*)&P_lds[w][r][c * 32 + qd * 8];
            lacc = __builtin_amdgcn_mfma_f32_16x16x32_bf16(pf, ones, lacc, 0, 0, 0);
#pragma unroll
            for (int ntd = 0; ntd < 4; ntd++) {
                bf16x8 vf = *(const bf16x8*)&Vbuf[(ntd * 2 + c) * 512 + lane * 8];
                oacc[ntd] = __builtin_amdgcn_mfma_f32_16x16x32_bf16(pf, vf, oacc[ntd], 0, 0, 0);
            }
        }

        __syncthreads();   // buf reads done before next iteration's staging
        cur ^= 1;
    }
#undef STAGE_K
#undef STAGE_V

    // ---- epilogue: O / l, store bf16 ----
    float rl[4];
#pragma unroll
    for (int reg = 0; reg < 4; reg++) rl[reg] = 1.f / lacc[reg];
#pragma unroll
    for (int ntd = 0; ntd < 4; ntd++)
#pragma unroll
        for (int reg = 0; reg < 4; reg++)
            O[(size_t)(q0w + qd * 4 + reg) * (NH * HD) + h * HD + ntd * 16 + r] =
                f2bf(oacc[ntd][reg] * rl[reg]);
}

// ---------------------------------------------------------------------------
// Launch: 5 dispatches.
// ---------------------------------------------------------------------------
extern "C" void kernel_launch(void* const* d_in, const int* in_sizes, int n_in,
                              void* d_out, int out_size, void* d_ws, size_t ws_size,
                              hipStream_t stream) {
    const float* hidden = (const float*)d_in[0];
    const float* Wq = (const float*)d_in[1];
    const float* Wk = (const float*)d_in[2];
    const float* Wv = (const float*)d_in[3];
    const float* Wo = (const float*)d_in[4];
    float* out = (float*)d_out;

    char* ws = (char*)d_ws;
    const size_t MB = 1024 * 1024;
    u16* Hh     = (u16*)(ws + 0 * MB);    // bf16 hidden          [2048][2048]   8 MB
    u16* WqkvT  = (u16*)(ws + 8 * MB);    // bf16 [Wq;Wk;Wv]^T    [3072][2048]  12 MB
    u16* WoT    = (u16*)(ws + 20 * MB);   // bf16 Wo^T            [2048][2048]   8 MB
    u16* Qh     = (u16*)(ws + 28 * MB);   // bf16 Q (no RoPE)     [2048][2048]   8 MB
    u16* Kh     = (u16*)(ws + 36 * MB);   // bf16 K (RoPE'd)      [2048][512]    2 MB
    u16* Vt     = (u16*)(ws + 38 * MB);   // bf16 V^T             [512][2048]    2 MB
    u16* Ob     = WqkvT;                  // attn out, reuses WqkvT (dead after QKV GEMM)

    cvt_bf16x8_kernel<<<(S_LEN * HID / 8 + 255) / 256, 256, 0, stream>>>(hidden, Hh, S_LEN * HID / 8);
    transpose_cvt4<<<dim3(HID / 32, HID / 32, 4), 256, 0, stream>>>(Wq, Wk, Wv, Wo, WqkvT, WoT);

    // fused QKV projection: N = 3072 (Q 2048 | K 512 | V 512), K-RoPE in epilogue
    gemm_bf16<1><<<dim3(3072 / 128, S_LEN / 128), 256, 0, stream>>>(Hh, WqkvT, nullptr, Qh, Kh, Vt, HID);

    attn_mfma<<<dim3(S_LEN / 128, NH), 512, 0, stream>>>(Qh, Kh, Vt, Ob);

    // output projection -> fp32 out
    gemm_bf16<0><<<dim3(HID / 128, S_LEN / 128), 256, 0, stream>>>(Ob, WoT, out, nullptr, nullptr, nullptr, HID);
}